// Round 22
// baseline (46.048 us; speedup 1.0000x reference)
//
#include <hip/hip_runtime.h>
#include <hip/hip_bf16.h>
#include <stdint.h>

#define N_ROWS 16384
#define O_ROWS 1024
#define K_DIM  512

typedef __bf16 bf16x4 __attribute__((ext_vector_type(4)));
typedef __bf16 bf16x8 __attribute__((ext_vector_type(8)));
typedef float  f32x4  __attribute__((ext_vector_type(4)));

__device__ __forceinline__ ushort f2bfu(float f) {
    __bf16 h = (__bf16)f;
    return __builtin_bit_cast(ushort, h);
}

#define BAR_LGKM()  do {                                        \
    asm volatile("s_waitcnt lgkmcnt(0)" ::: "memory");          \
    __builtin_amdgcn_s_barrier();                               \
} while (0)

// ---------------------------------------------------------------------------
// Round 22: interleave AND 2 blocks/CU, via BK=32 full double-buffer (48 KB).
// Measured: interleave +9% at iso-occupancy (r20 48.7 -> r21 44.2); second
// block +17% (r21 -> r16 40.6). BK=64 dbuf (96KB) forced 1 blk; BK=32 dbuf
// fits 2. LDS rows stay 128B via ROW-PAIR packing (rows r and r+128 share a
// row: lr=r&127, byte+=(r>>7)*64) so the proven ((r&7)<<4) XOR swizzle and
// its 2-way-max conflicts are preserved.
//  - 256x128 tile, 16 kt of K=32, ONE lgkm barrier per kt.
//  - per kt: {issue loads(kt+1) -> ds_read a4/b4 -> 8 MFMA ->
//             cvt+sumsq+stage(kt+1)->nxt -> 8 MFMA -> BAR}
//  - 512 thr, 8 waves (4x2), 64x64 wave tiles, acc 4x4 = 64 AGPR.
//  - bijective XCD swizzle, extended-K-tile epilogue, #pragma unroll 1.
// ---------------------------------------------------------------------------
__global__ __launch_bounds__(512) void quadra_kernel(
    const float* __restrict__ x, const float* __restrict__ mean,
    float* __restrict__ out)
{
    __shared__ ushort sA[2][128 * 64];   // A: 256 rows row-pair-packed, 32 KiB
    __shared__ ushort sB[2][64 * 64];    // B: 128 rows row-pair-packed, 16 KiB

    const int bid  = blockIdx.x;                // 0..511
    const int t    = (bid & 7) * 64 + (bid >> 3);
    const int brow = (t >> 3) * 256;
    const int bcol = (t & 7) * 128;

    const int tid  = threadIdx.x;
    const int lane = tid & 63;
    const int wid  = tid >> 6;                  // 0..7
    const int wr = wid >> 1, wc = wid & 1;      // 4x2 wave grid, 64x64 out each
    const int cl = lane & 15, hi = lane >> 4;

    f32x4 acc[4][4] = {};

    // staging: r0 = tid>>3 (0..63), q = tid&7 covers k-quad q*4 in [0,32).
    // thread stages A rows {r0+64i : i=0..3}, B rows {r0+64i : i=0..1}.
    const int r0 = tid >> 3;
    const int q  = tid & 7;

    const float* gA = x    + (size_t)(brow + r0) * K_DIM + q * 4;
    const float* gB = mean + (size_t)(bcol + r0) * K_DIM + q * 4;

    float asq[4] = {0.f, 0.f, 0.f, 0.f};
    float bsq[2] = {0.f, 0.f};

    f32x4 pa[4], pb[2];

    // ---- prologue: load + stage kt=0 into buf 0 ----
    #pragma unroll
    for (int i = 0; i < 4; ++i)
        pa[i] = *(const f32x4*)(gA + (size_t)(i * 64) * K_DIM);
    #pragma unroll
    for (int i = 0; i < 2; ++i)
        pb[i] = *(const f32x4*)(gB + (size_t)(i * 64) * K_DIM);

    #pragma unroll
    for (int i = 0; i < 4; ++i) {
        f32x4 v = pa[i];
        asq[i] += v[0]*v[0] + v[1]*v[1] + v[2]*v[2] + v[3]*v[3];
        bf16x4 cv;
        cv[0] = (__bf16)v[0]; cv[1] = (__bf16)v[1];
        cv[2] = (__bf16)v[2]; cv[3] = (__bf16)v[3];
        const int r  = r0 + i * 64;
        const int by = ((r >> 7) * 64 + q * 8) ^ ((r & 7) << 4);
        *(bf16x4*)(&sA[0][0] + (r & 127) * 64 + (by >> 1)) = cv;
    }
    #pragma unroll
    for (int i = 0; i < 2; ++i) {
        f32x4 v = pb[i];
        bsq[i] += v[0]*v[0] + v[1]*v[1] + v[2]*v[2] + v[3]*v[3];
        bf16x4 cv;
        cv[0] = (__bf16)(v[0] * -2.0f); cv[1] = (__bf16)(v[1] * -2.0f);
        cv[2] = (__bf16)(v[2] * -2.0f); cv[3] = (__bf16)(v[3] * -2.0f);
        const int r  = r0 + i * 64;
        const int by = ((r >> 6) * 64 + q * 8) ^ ((r & 7) << 4);
        *(bf16x4*)(&sB[0][0] + (r & 63) * 64 + (by >> 1)) = cv;
    }
    BAR_LGKM();

    #pragma unroll 1
    for (int kt = 0; kt < 16; ++kt) {
        const int cur = kt & 1;
        ushort* bufA = &sA[cur][0];
        ushort* bufB = &sB[cur][0];
        ushort* nxtA = &sA[cur ^ 1][0];
        ushort* nxtB = &sB[cur ^ 1][0];

        // issue loads for kt+1 (fly under the first MFMA half)
        if (kt < 15) {
            #pragma unroll
            for (int i = 0; i < 4; ++i)
                pa[i] = *(const f32x4*)(gA + (size_t)(i * 64) * K_DIM + (kt + 1) * 32);
            #pragma unroll
            for (int i = 0; i < 2; ++i)
                pb[i] = *(const f32x4*)(gB + (size_t)(i * 64) * K_DIM + (kt + 1) * 32);
        }

        // ds_read fragments (K=32: one 16x16x32 per frag pair)
        bf16x8 a[4], b[4];
        #pragma unroll
        for (int m = 0; m < 4; ++m) {
            const int rr = wr*64 + m*16 + cl;
            const int by = ((rr >> 7) * 64 + hi * 16) ^ ((rr & 7) << 4);
            a[m] = *(const bf16x8*)(bufA + (rr & 127) * 64 + (by >> 1));
        }
        #pragma unroll
        for (int n = 0; n < 4; ++n) {
            const int rr = wc*64 + n*16 + cl;
            const int by = ((rr >> 6) * 64 + hi * 16) ^ ((rr & 7) << 4);
            b[n] = *(const bf16x8*)(bufB + (rr & 63) * 64 + (by >> 1));
        }

        // first MFMA half (m = 0,1)
        #pragma unroll
        for (int m = 0; m < 2; ++m)
            #pragma unroll
            for (int n = 0; n < 4; ++n)
                acc[m][n] = __builtin_amdgcn_mfma_f32_16x16x32_bf16(
                    a[m], b[n], acc[m][n], 0, 0, 0);

        // stage kt+1 into the other buffer (hides under MFMA)
        if (kt < 15) {
            #pragma unroll
            for (int i = 0; i < 4; ++i) {
                f32x4 v = pa[i];
                asq[i] += v[0]*v[0] + v[1]*v[1] + v[2]*v[2] + v[3]*v[3];
                bf16x4 cv;
                cv[0] = (__bf16)v[0]; cv[1] = (__bf16)v[1];
                cv[2] = (__bf16)v[2]; cv[3] = (__bf16)v[3];
                const int r  = r0 + i * 64;
                const int by = ((r >> 7) * 64 + q * 8) ^ ((r & 7) << 4);
                *(bf16x4*)(nxtA + (r & 127) * 64 + (by >> 1)) = cv;
            }
            #pragma unroll
            for (int i = 0; i < 2; ++i) {
                f32x4 v = pb[i];
                bsq[i] += v[0]*v[0] + v[1]*v[1] + v[2]*v[2] + v[3]*v[3];
                bf16x4 cv;
                cv[0] = (__bf16)(v[0] * -2.0f); cv[1] = (__bf16)(v[1] * -2.0f);
                cv[2] = (__bf16)(v[2] * -2.0f); cv[3] = (__bf16)(v[3] * -2.0f);
                const int r  = r0 + i * 64;
                const int by = ((r >> 6) * 64 + q * 8) ^ ((r & 7) << 4);
                *(bf16x4*)(nxtB + (r & 63) * 64 + (by >> 1)) = cv;
            }
        }

        // second MFMA half (m = 2,3)
        #pragma unroll
        for (int m = 2; m < 4; ++m)
            #pragma unroll
            for (int n = 0; n < 4; ++n)
                acc[m][n] = __builtin_amdgcn_mfma_f32_16x16x32_bf16(
                    a[m], b[n], acc[m][n], 0, 0, 0);

        BAR_LGKM();   // my reads of buf[cur] drained; kt+2 may overwrite it
    }

    // Extended K-tile (aliased into sA, dead after the loop):
    //   sAe[row(256)] = [xsq, 1, 0 x30]   sBe[row(128)] = [1, msq, 0 x30]
    ushort* sAe = &sA[0][0];              // 16 KB
    ushort* sBe = &sA[1][0];              //  8 KB (within sA[1]'s 16 KB)
    #pragma unroll
    for (int i = 0; i < 4; ++i) {
        float sa = asq[i];
        #pragma unroll
        for (int msk = 1; msk < 8; msk <<= 1) sa += __shfl_xor(sa, msk);
        uint2 aw = {0u, 0u};
        if (q == 0) aw.x = (uint32_t)f2bfu(sa) | (0x3F80u << 16);  // [xsq, 1.0]
        *(uint2*)(sAe + (r0 + i * 64) * 32 + q * 4) = aw;
    }
    #pragma unroll
    for (int i = 0; i < 2; ++i) {
        float sb = bsq[i];
        #pragma unroll
        for (int msk = 1; msk < 8; msk <<= 1) sb += __shfl_xor(sb, msk);
        uint2 bw = {0u, 0u};
        if (q == 0) bw.x = 0x3F80u | ((uint32_t)f2bfu(sb) << 16);  // [1.0, msq]
        *(uint2*)(sBe + (r0 + i * 64) * 32 + q * 4) = bw;
    }
    BAR_LGKM();

    {   // extra MFMA: adds xsq[r] + msq[o] into every accumulator element
        bf16x8 a[4], b[4];
        #pragma unroll
        for (int m = 0; m < 4; ++m)
            a[m] = *(const bf16x8*)(sAe + (wr*64 + m*16 + cl) * 32 + hi * 8);
        #pragma unroll
        for (int n = 0; n < 4; ++n)
            b[n] = *(const bf16x8*)(sBe + (wc*64 + n*16 + cl) * 32 + hi * 8);
        #pragma unroll
        for (int m = 0; m < 4; ++m)
            #pragma unroll
            for (int n = 0; n < 4; ++n)
                acc[m][n] = __builtin_amdgcn_mfma_f32_16x16x32_bf16(
                    a[m], b[n], acc[m][n], 0, 0, 0);
    }

    // epilogue: C/D layout col = lane&15, row = (lane>>4)*4 + j
    #pragma unroll
    for (int m = 0; m < 4; ++m) {
        #pragma unroll
        for (int j = 0; j < 4; ++j) {
            const int grow = brow + wr*64 + m*16 + hi*4 + j;
            float* orow = out + (size_t)grow * O_ROWS + bcol + wc*64 + cl;
            #pragma unroll
            for (int n = 0; n < 4; ++n)
                orow[n * 16] = rsqrtf(acc[m][n][j]);
        }
    }
}

extern "C" void kernel_launch(void* const* d_in, const int* in_sizes, int n_in,
                              void* d_out, int out_size, void* d_ws, size_t ws_size,
                              hipStream_t stream) {
    const float* x    = (const float*)d_in[0];
    const float* mean = (const float*)d_in[1];
    float* out = (float*)d_out;

    quadra_kernel<<<dim3((N_ROWS / 256) * (O_ROWS / 128)), 512, 0, stream>>>(
        x, mean, out);
}